// Round 5
// baseline (625.985 us; speedup 1.0000x reference)
//
#include <hip/hip_runtime.h>
#include <hip/hip_bf16.h>
#include <math.h>

// Problem dims
constexpr int BD = 32;
constexpr int SD = 512;
constexpr int RD = 49;
constexpr int HD = 768;
constexpr int NB = HD / 64;    // 12 n-blocks in the score GEMMs
constexpr int NP = NB * 2;     // 24 partial slots per row (2 column-halves per wave pair)
constexpr int MT = BD * SD;    // 16384
constexpr int MI = BD * RD;    // 1568 (gemm pads to 1600 rows)

typedef __bf16 bf16;
typedef __bf16 bf16x8 __attribute__((ext_vector_type(8)));
typedef float f32x4 __attribute__((ext_vector_type(4)));
typedef float f32x8 __attribute__((ext_vector_type(8)));

// ---------------------------------------------------------------------------
// Score GEMM: part[m][by*2+half] = sum_{n in 32-col half} tanh((A@W)[m,n])*vec[n]
// A: M x K fp32 row-major, W: K x N fp32 row-major, vec: N fp32.
// fp32 inputs converted to bf16 while staging into LDS; 16x16x32 bf16 MFMA,
// fp32 accum. 64x64 tile / 256-thread block, 4 waves of 32x32 (2x2 MFMA).
// Waves (wm,0) and (wm,32) cover the same rows -> disjoint partial slots
// (w&1) to avoid the store race.
// ---------------------------------------------------------------------------
__global__ __launch_bounds__(256) void gemm_tanh_dot(
    const float* __restrict__ A, const float* __restrict__ W,
    const float* __restrict__ vec, float* __restrict__ part,
    int M, int N, int K)
{
    __shared__ __align__(16) bf16 As[64][40];  // [m][k], 80B rows (16B-aligned)
    __shared__ __align__(16) bf16 Bs[64][40];  // [n][k]

    const int t = threadIdx.x;
    const int m0 = blockIdx.x * 64;
    const int n0 = blockIdx.y * 64;
    const int w = t >> 6, lane = t & 63;
    const int quad = lane >> 4, l16 = lane & 15;
    const int wm = (w >> 1) * 32, wn = (w & 1) * 32;

    // staging assignments (8 contiguous elements per thread)
    const int ar = t >> 2, ak = (t & 3) * 8;   // A tile: 64 rows x 32 k
    const int bk = t >> 3, bn = (t & 7) * 8;   // W tile: 32 k x 64 n

    f32x4 acc[2][2] = {};

    for (int kk = 0; kk < K; kk += 32) {
        f32x8 af = {};
        const int gm = m0 + ar;
        if (gm < M) {
            const float* ap = A + (size_t)gm * K + kk + ak;
            af[0]=ap[0]; af[1]=ap[1]; af[2]=ap[2]; af[3]=ap[3];
            af[4]=ap[4]; af[5]=ap[5]; af[6]=ap[6]; af[7]=ap[7];
        }
        const float* wp = W + (size_t)(kk + bk) * N + n0 + bn;
        f32x8 wf;
        wf[0]=wp[0]; wf[1]=wp[1]; wf[2]=wp[2]; wf[3]=wp[3];
        wf[4]=wp[4]; wf[5]=wp[5]; wf[6]=wp[6]; wf[7]=wp[7];

        bf16x8 av, wv;
        #pragma unroll
        for (int j = 0; j < 8; ++j) { av[j] = (bf16)af[j]; wv[j] = (bf16)wf[j]; }

        __syncthreads();   // previous iteration's LDS reads done
        *(bf16x8*)(&As[ar][ak]) = av;
        #pragma unroll
        for (int j = 0; j < 8; ++j) Bs[bn + j][bk] = wv[j];
        __syncthreads();

        const bf16x8 a0 = *(const bf16x8*)(&As[wm + l16][quad * 8]);
        const bf16x8 a1 = *(const bf16x8*)(&As[wm + 16 + l16][quad * 8]);
        const bf16x8 b0 = *(const bf16x8*)(&Bs[wn + l16][quad * 8]);
        const bf16x8 b1 = *(const bf16x8*)(&Bs[wn + 16 + l16][quad * 8]);
        acc[0][0] = __builtin_amdgcn_mfma_f32_16x16x32_bf16(a0, b0, acc[0][0], 0, 0, 0);
        acc[0][1] = __builtin_amdgcn_mfma_f32_16x16x32_bf16(a0, b1, acc[0][1], 0, 0, 0);
        acc[1][0] = __builtin_amdgcn_mfma_f32_16x16x32_bf16(a1, b0, acc[1][0], 0, 0, 0);
        acc[1][1] = __builtin_amdgcn_mfma_f32_16x16x32_bf16(a1, b1, acc[1][1], 0, 0, 0);
    }

    // epilogue: C/D layout col=lane&15, row=quad*4+reg
    #pragma unroll
    for (int ti = 0; ti < 2; ++ti)
      #pragma unroll
      for (int reg = 0; reg < 4; ++reg) {
          float p = 0.f;
          #pragma unroll
          for (int tj = 0; tj < 2; ++tj) {
              const int gn = n0 + wn + tj * 16 + l16;
              p += tanhf(acc[ti][tj][reg]) * vec[gn];
          }
          p += __shfl_xor(p, 1);
          p += __shfl_xor(p, 2);
          p += __shfl_xor(p, 4);
          p += __shfl_xor(p, 8);
          const int gm = m0 + wm + ti * 16 + quad * 4 + reg;  // < gridDim.x*64
          if (l16 == 0) part[(size_t)gm * NP + blockIdx.y * 2 + (w & 1)] = p;
      }
}

// score[m] = sum_j part[m*NP+j]
__global__ __launch_bounds__(256) void reduce_nb(const float* __restrict__ part,
                                                 float* __restrict__ score, int M) {
    const int m = blockIdx.x * 256 + threadIdx.x;
    if (m < M) {
        float s = 0.f;
        #pragma unroll
        for (int j = 0; j < NP; ++j) s += part[(size_t)m * NP + j];
        score[m] = s;
    }
}

// softmax over R=49 per batch (one wave per batch); safe in-place (sc==p1)
__global__ __launch_bounds__(64) void softmax_p1(const float* sc, float* p1) {
    const int b = blockIdx.x, l = threadIdx.x;
    float x = (l < RD) ? sc[b * RD + l] : -1e30f;
    float m = x;
    for (int off = 32; off; off >>= 1) m = fmaxf(m, __shfl_xor(m, off));
    float e = (l < RD) ? expf(x - m) : 0.f;
    float s = e;
    for (int off = 32; off; off >>= 1) s += __shfl_xor(s, off);
    if (l < RD) p1[b * RD + l] = e / s;
}

// softmax over S=512 per batch (256 threads, 2 elems each); safe in-place
__global__ __launch_bounds__(256) void softmax_p2(const float* sc, float* p2) {
    const int b = blockIdx.x, t = threadIdx.x;
    __shared__ float red[4];
    const float x0 = sc[b * SD + t], x1 = sc[b * SD + 256 + t];
    float m = fmaxf(x0, x1);
    for (int off = 32; off; off >>= 1) m = fmaxf(m, __shfl_xor(m, off));
    if ((t & 63) == 0) red[t >> 6] = m;
    __syncthreads();
    m = fmaxf(fmaxf(red[0], red[1]), fmaxf(red[2], red[3]));
    const float e0 = expf(x0 - m), e1 = expf(x1 - m);
    float s = e0 + e1;
    for (int off = 32; off; off >>= 1) s += __shfl_xor(s, off);
    __syncthreads();
    if ((t & 63) == 0) red[t >> 6] = s;
    __syncthreads();
    s = red[0] + red[1] + red[2] + red[3];
    p2[b * SD + t] = e0 / s;
    p2[b * SD + 256 + t] = e1 / s;
}

// Y[b,h] = sum_j P[b,j] * X[b,j,h]
__global__ __launch_bounds__(256) void wsum_rows(const float* __restrict__ P,
                                                 const float* __restrict__ X,
                                                 float* __restrict__ Y, int J) {
    const int b = blockIdx.x;
    const int h = blockIdx.y * 256 + threadIdx.x;
    __shared__ float Ps[SD];
    for (int j = threadIdx.x; j < J; j += 256) Ps[j] = P[b * J + j];
    __syncthreads();
    float acc = 0.f;
    const float* Xb = X + (size_t)b * J * HD + h;
    for (int j = 0; j < J; ++j) acc += Ps[j] * Xb[(size_t)j * HD];
    Y[b * HD + h] = acc;
}

// Per-batch fused GMF: ni/nt/gate/mix + T = tanh(mm@fr_w+fr_b) + s_mm scalar.
__global__ __launch_bounds__(256) void fused_batch(
    const float* __restrict__ aimg, const float* __restrict__ atxt,
    const float* __restrict__ gi_w, const float* __restrict__ gi_b,
    const float* __restrict__ gt_w, const float* __restrict__ gt_b,
    const float* __restrict__ gg_w, const float* __restrict__ gg_b,
    const float* __restrict__ fr_w, const float* __restrict__ fr_b,
    const float* __restrict__ v_m, const float* __restrict__ c_m,
    const float* __restrict__ fg_b,
    float* __restrict__ T, float* __restrict__ s_mm)
{
    __shared__ float ai[HD], at[HD], ni[HD], nt[HD], mmrow[HD];
    __shared__ float red[4];
    __shared__ float gsh;
    const int b = blockIdx.x, t = threadIdx.x;
    for (int n = t; n < HD; n += 256) { ai[n] = aimg[b * HD + n]; at[n] = atxt[b * HD + n]; }
    __syncthreads();
    for (int n = t; n < HD; n += 256) {
        float a1 = 0.f, a2 = 0.f;
        for (int h = 0; h < HD; ++h) {
            a1 += ai[h] * gi_w[(size_t)h * HD + n];
            a2 += at[h] * gt_w[(size_t)h * HD + n];
        }
        ni[n] = tanhf(a1 + gi_b[n]);
        nt[n] = tanhf(a2 + gt_b[n]);
    }
    __syncthreads();
    float acc = 0.f;
    for (int n = t; n < HD; n += 256) acc += ni[n] * gg_w[n] + nt[n] * gg_w[HD + n];
    for (int off = 32; off; off >>= 1) acc += __shfl_xor(acc, off);
    if ((t & 63) == 0) red[t >> 6] = acc;
    __syncthreads();
    if (t == 0) gsh = 1.f / (1.f + expf(-(red[0] + red[1] + red[2] + red[3] + gg_b[0])));
    __syncthreads();
    const float g = gsh;
    for (int n = t; n < HD; n += 256) mmrow[n] = g * ni[n] + (1.f - g) * nt[n];
    __syncthreads();
    for (int n = t; n < HD; n += 256) {
        float a = 0.f;
        for (int h = 0; h < HD; ++h) a += mmrow[h] * fr_w[(size_t)h * HD + n];
        T[b * HD + n] = tanhf(a + fr_b[n]);
    }
    float a2 = 0.f;
    for (int n = t; n < HD; n += 256) a2 += mmrow[n] * v_m[n];
    for (int off = 32; off; off >>= 1) a2 += __shfl_xor(a2, off);
    __syncthreads();
    if ((t & 63) == 0) red[t >> 6] = a2;
    __syncthreads();
    if (t == 0) s_mm[b] = red[0] + red[1] + red[2] + red[3] + *c_m + fg_b[0];
}

// v_f[h] = ft_w[h,:].fg_w[:H]; v_m[h] = fm_w[h,:].fg_w[H:]; c_m = fm_b.fg_w[H:]
__global__ __launch_bounds__(256) void vf_vm_kernel(const float* __restrict__ ft_w,
                                                    const float* __restrict__ fm_w,
                                                    const float* __restrict__ fm_b,
                                                    const float* __restrict__ fg_w,
                                                    float* __restrict__ v_f,
                                                    float* __restrict__ v_m,
                                                    float* __restrict__ c_m) {
    const int g = blockIdx.x * 256 + threadIdx.x;
    if (g < HD) {
        float a = 0.f;
        for (int h2 = 0; h2 < HD; ++h2) a += ft_w[(size_t)g * HD + h2] * fg_w[h2];
        v_f[g] = a;
    } else if (g < 2 * HD) {
        const int r = g - HD;
        float a = 0.f;
        for (int h2 = 0; h2 < HD; ++h2) a += fm_w[(size_t)r * HD + h2] * fg_w[HD + h2];
        v_m[r] = a;
    } else if (g == 2 * HD) {
        float a = 0.f;
        for (int h = 0; h < HD; ++h) a += fm_b[h] * fg_w[HD + h];
        *c_m = a;
    }
}

// s_txt[row] = text[row,:] . v_f   (one wave per row)
__global__ __launch_bounds__(256) void stxt_kernel(const float* __restrict__ text,
                                                   const float* __restrict__ v_f,
                                                   float* __restrict__ s_txt) {
    const int row = blockIdx.x * 4 + (threadIdx.x >> 6);
    const int lane = threadIdx.x & 63;
    const float* tr = text + (size_t)row * HD;
    float acc = 0.f;
    #pragma unroll
    for (int i = 0; i < HD / 64; ++i)
        acc += tr[lane + 64 * i] * v_f[lane + 64 * i];
    for (int off = 32; off; off >>= 1) acc += __shfl_xor(acc, off);
    if (lane == 0) s_txt[row] = acc;
}

// out[b,s,h] = sigmoid(s_txt[b,s] + s_mm[b]) * T[b,h]   (4 fp32 per thread)
// Reads ONLY ws buffers; overwrites the whole of d_out (incl. scratch regions).
__global__ __launch_bounds__(256) void out_kernel(const float* __restrict__ s_txt,
                                                  const float* __restrict__ s_mm,
                                                  const float* __restrict__ T,
                                                  float* __restrict__ out) {
    const size_t idx = ((size_t)blockIdx.x * 256 + threadIdx.x) * 4;
    const int h = (int)(idx % HD);       // HD % 4 == 0: chunk stays in one row
    const int bs = (int)(idx / HD);
    const int b = bs >> 9;  // /SD
    float f = s_txt[bs] + s_mm[b];
    f = 1.f / (1.f + expf(-f));
    const float* Tp = T + b * HD + h;
    f32x4 o;
    o[0] = f * Tp[0]; o[1] = f * Tp[1]; o[2] = f * Tp[2]; o[3] = f * Tp[3];
    *(f32x4*)(out + idx) = o;
}

// ---------------------------------------------------------------------------
extern "C" void kernel_launch(void* const* d_in, const int* in_sizes, int n_in,
                              void* d_out, int out_size, void* d_ws, size_t ws_size,
                              hipStream_t stream) {
    const float* text = (const float*)d_in[0];
    const float* img  = (const float*)d_in[1];
    const float* i1_w = (const float*)d_in[4];
    const float* a1_w = (const float*)d_in[5];
    const float* t2_w = (const float*)d_in[7];
    const float* a2_w = (const float*)d_in[10];
    const float* gt_w = (const float*)d_in[12];
    const float* gt_b = (const float*)d_in[13];
    const float* gi_w = (const float*)d_in[14];
    const float* gi_b = (const float*)d_in[15];
    const float* gg_w = (const float*)d_in[16];
    const float* gg_b = (const float*)d_in[17];
    const float* ft_w = (const float*)d_in[18];
    const float* fm_w = (const float*)d_in[19];
    const float* fm_b = (const float*)d_in[20];
    const float* fg_w = (const float*)d_in[21];
    const float* fg_b = (const float*)d_in[22];
    const float* fr_w = (const float*)d_in[23];
    const float* fr_b = (const float*)d_in[24];
    float* out = (float*)d_out;

    // ---- scratch inside d_out (12.58M floats; all uses precede out_kernel) ----
    float* sc_ = out;
    float* i_part = sc_;                 // 1600*24 = 38400
    float* k_part = sc_ + 38400;         // 16384*24 = 393216
    float* i_sc   = sc_ + 431616;        // 1600 (softmax in-place -> p1)
    float* k_sc   = sc_ + 433216;        // 16384 (softmax in-place -> p2)
    float* aimg   = sc_ + 449600;        // 24576
    float* atxt   = sc_ + 474176;        // 24576
    float* v_f    = sc_ + 498752;        // 768
    float* v_m    = sc_ + 499520;        // 768
    float* c_m    = sc_ + 500288;        // 1   (total ~500K << 12.58M)

    // ---- ws holds only what out_kernel reads (164 KB) ----
    float* ws     = (float*)d_ws;
    float* s_txt  = ws;                  // 16384
    float* s_mm   = ws + 16384;          // 32 (+pad)
    float* T      = ws + 16448;          // 24576  -> total 41024 floats = 164 KB

    // 1/2. score GEMMs (partials per n-block x column-half)
    gemm_tanh_dot<<<dim3((MI + 63) / 64, NB), dim3(256), 0, stream>>>(
        img, i1_w, a1_w + HD, i_part, MI, HD, HD);
    gemm_tanh_dot<<<dim3(MT / 64, NB), dim3(256), 0, stream>>>(
        text, t2_w, a2_w + HD, k_part, MT, HD, HD);
    reduce_nb<<<dim3(7), dim3(256), 0, stream>>>(i_part, i_sc, MI);
    reduce_nb<<<dim3(MT / 256), dim3(256), 0, stream>>>(k_part, k_sc, MT);
    // 3. rank-1 collapses of the filtration gate
    vf_vm_kernel<<<dim3(7), dim3(256), 0, stream>>>(ft_w, fm_w, fm_b, fg_w, v_f, v_m, c_m);
    // 4/5. softmaxes, in-place (query-side terms cancel along softmax axis)
    softmax_p1<<<dim3(BD), dim3(64), 0, stream>>>(i_sc, i_sc);
    softmax_p2<<<dim3(BD), dim3(256), 0, stream>>>(k_sc, k_sc);
    // 6/7. attended rows (s-independent -> one row per batch)
    wsum_rows<<<dim3(BD, HD / 256), dim3(256), 0, stream>>>(i_sc, img, aimg, RD);
    wsum_rows<<<dim3(BD, HD / 256), dim3(256), 0, stream>>>(k_sc, text, atxt, SD);
    // 8. fused GMF + filtration scalars per batch
    fused_batch<<<dim3(BD), dim3(256), 0, stream>>>(
        aimg, atxt, gi_w, gi_b, gt_w, gt_b, gg_w, gg_b, fr_w, fr_b,
        v_m, c_m, fg_b, T, s_mm);
    // 9. per-(b,s) text gate term
    stxt_kernel<<<dim3(MT / 4), dim3(256), 0, stream>>>(text, v_f, s_txt);
    // 10. output (reads ws only; overwrites all of d_out)
    out_kernel<<<dim3((MT * HD / 4) / 256), dim3(256), 0, stream>>>(s_txt, s_mm, T, out);
}

// Round 6
// 349.243 us; speedup vs baseline: 1.7924x; 1.7924x over previous
//
#include <hip/hip_runtime.h>
#include <hip/hip_bf16.h>
#include <math.h>

// Problem dims
constexpr int BD = 32;
constexpr int SD = 512;
constexpr int RD = 49;
constexpr int HD = 768;
constexpr int NB = HD / 64;    // 12 n-blocks in the score GEMMs
constexpr int NP = NB * 2;     // 24 partial slots per row
constexpr int MT = BD * SD;    // 16384
constexpr int MI = BD * RD;    // 1568 (gemm pads to 1600 rows)

typedef __bf16 bf16;
typedef __bf16 bf16x8 __attribute__((ext_vector_type(8)));
typedef float f32x4 __attribute__((ext_vector_type(4)));
typedef float f32x8 __attribute__((ext_vector_type(8)));

// ---------------------------------------------------------------------------
// Score GEMM: part[m][by*2+half] = sum_{n in 32-col half} tanh((A@W)[m,n])*vec[n]
// ---------------------------------------------------------------------------
__global__ __launch_bounds__(256) void gemm_tanh_dot(
    const float* __restrict__ A, const float* __restrict__ W,
    const float* __restrict__ vec, float* __restrict__ part,
    int M, int N, int K)
{
    __shared__ __align__(16) bf16 As[64][40];
    __shared__ __align__(16) bf16 Bs[64][40];

    const int t = threadIdx.x;
    const int m0 = blockIdx.x * 64;
    const int n0 = blockIdx.y * 64;
    const int w = t >> 6, lane = t & 63;
    const int quad = lane >> 4, l16 = lane & 15;
    const int wm = (w >> 1) * 32, wn = (w & 1) * 32;

    const int ar = t >> 2, ak = (t & 3) * 8;   // A tile: 64 rows x 32 k
    const int bk = t >> 3, bn = (t & 7) * 8;   // W tile: 32 k x 64 n

    f32x4 acc[2][2] = {};

    for (int kk = 0; kk < K; kk += 32) {
        f32x8 af = {};
        const int gm = m0 + ar;
        if (gm < M) {
            const float* ap = A + (size_t)gm * K + kk + ak;
            af[0]=ap[0]; af[1]=ap[1]; af[2]=ap[2]; af[3]=ap[3];
            af[4]=ap[4]; af[5]=ap[5]; af[6]=ap[6]; af[7]=ap[7];
        }
        const float* wp = W + (size_t)(kk + bk) * N + n0 + bn;
        f32x8 wf;
        wf[0]=wp[0]; wf[1]=wp[1]; wf[2]=wp[2]; wf[3]=wp[3];
        wf[4]=wp[4]; wf[5]=wp[5]; wf[6]=wp[6]; wf[7]=wp[7];

        bf16x8 av, wv;
        #pragma unroll
        for (int j = 0; j < 8; ++j) { av[j] = (bf16)af[j]; wv[j] = (bf16)wf[j]; }

        __syncthreads();
        *(bf16x8*)(&As[ar][ak]) = av;
        #pragma unroll
        for (int j = 0; j < 8; ++j) Bs[bn + j][bk] = wv[j];
        __syncthreads();

        const bf16x8 a0 = *(const bf16x8*)(&As[wm + l16][quad * 8]);
        const bf16x8 a1 = *(const bf16x8*)(&As[wm + 16 + l16][quad * 8]);
        const bf16x8 b0 = *(const bf16x8*)(&Bs[wn + l16][quad * 8]);
        const bf16x8 b1 = *(const bf16x8*)(&Bs[wn + 16 + l16][quad * 8]);
        acc[0][0] = __builtin_amdgcn_mfma_f32_16x16x32_bf16(a0, b0, acc[0][0], 0, 0, 0);
        acc[0][1] = __builtin_amdgcn_mfma_f32_16x16x32_bf16(a0, b1, acc[0][1], 0, 0, 0);
        acc[1][0] = __builtin_amdgcn_mfma_f32_16x16x32_bf16(a1, b0, acc[1][0], 0, 0, 0);
        acc[1][1] = __builtin_amdgcn_mfma_f32_16x16x32_bf16(a1, b1, acc[1][1], 0, 0, 0);
    }

    #pragma unroll
    for (int ti = 0; ti < 2; ++ti)
      #pragma unroll
      for (int reg = 0; reg < 4; ++reg) {
          float p = 0.f;
          #pragma unroll
          for (int tj = 0; tj < 2; ++tj) {
              const int gn = n0 + wn + tj * 16 + l16;
              p += tanhf(acc[ti][tj][reg]) * vec[gn];
          }
          p += __shfl_xor(p, 1);
          p += __shfl_xor(p, 2);
          p += __shfl_xor(p, 4);
          p += __shfl_xor(p, 8);
          const int gm = m0 + wm + ti * 16 + quad * 4 + reg;
          if (l16 == 0) part[(size_t)gm * NP + blockIdx.y * 2 + (w & 1)] = p;
      }
}

// score[m] = sum_j part[m*NP+j]
__global__ __launch_bounds__(256) void reduce_nb(const float* __restrict__ part,
                                                 float* __restrict__ score, int M) {
    const int m = blockIdx.x * 256 + threadIdx.x;
    if (m < M) {
        float s = 0.f;
        #pragma unroll
        for (int j = 0; j < NP; ++j) s += part[(size_t)m * NP + j];
        score[m] = s;
    }
}

// softmax over R=49 per batch; safe in-place
__global__ __launch_bounds__(64) void softmax_p1(const float* sc, float* p1) {
    const int b = blockIdx.x, l = threadIdx.x;
    float x = (l < RD) ? sc[b * RD + l] : -1e30f;
    float m = x;
    for (int off = 32; off; off >>= 1) m = fmaxf(m, __shfl_xor(m, off));
    float e = (l < RD) ? expf(x - m) : 0.f;
    float s = e;
    for (int off = 32; off; off >>= 1) s += __shfl_xor(s, off);
    if (l < RD) p1[b * RD + l] = e / s;
}

// softmax over S=512 per batch; safe in-place
__global__ __launch_bounds__(256) void softmax_p2(const float* sc, float* p2) {
    const int b = blockIdx.x, t = threadIdx.x;
    __shared__ float red[4];
    const float x0 = sc[b * SD + t], x1 = sc[b * SD + 256 + t];
    float m = fmaxf(x0, x1);
    for (int off = 32; off; off >>= 1) m = fmaxf(m, __shfl_xor(m, off));
    if ((t & 63) == 0) red[t >> 6] = m;
    __syncthreads();
    m = fmaxf(fmaxf(red[0], red[1]), fmaxf(red[2], red[3]));
    const float e0 = expf(x0 - m), e1 = expf(x1 - m);
    float s = e0 + e1;
    for (int off = 32; off; off >>= 1) s += __shfl_xor(s, off);
    __syncthreads();
    if ((t & 63) == 0) red[t >> 6] = s;
    __syncthreads();
    s = red[0] + red[1] + red[2] + red[3];
    p2[b * SD + t] = e0 / s;
    p2[b * SD + 256 + t] = e1 / s;
}

// Y[b,h] = sum_j P[b,j] * X[b,j,h]  (small J; used for img, J=49)
__global__ __launch_bounds__(256) void wsum_rows(const float* __restrict__ P,
                                                 const float* __restrict__ X,
                                                 float* __restrict__ Y, int J) {
    const int b = blockIdx.x;
    const int h = blockIdx.y * 256 + threadIdx.x;
    __shared__ float Ps[SD];
    for (int j = threadIdx.x; j < J; j += 256) Ps[j] = P[b * J + j];
    __syncthreads();
    float acc = 0.f;
    const float* Xb = X + (size_t)b * J * HD + h;
    for (int j = 0; j < J; ++j) acc += Ps[j] * Xb[(size_t)j * HD];
    Y[b * HD + h] = acc;
}

// text wsum, j-split 4-way: part[(b*4+q)*HD + h] = sum_{j in q} P[b,j] X[b,j,h]
__global__ __launch_bounds__(256) void wsum_part(const float* __restrict__ P,
                                                 const float* __restrict__ X,
                                                 float* __restrict__ part) {
    const int b = blockIdx.x;
    const int h = blockIdx.y * 256 + threadIdx.x;
    const int q = blockIdx.z;
    __shared__ float Ps[128];
    if (threadIdx.x < 128) Ps[threadIdx.x] = P[b * SD + q * 128 + threadIdx.x];
    __syncthreads();
    float acc = 0.f;
    const float* Xb = X + (size_t)b * SD * HD + (size_t)(q * 128) * HD + h;
    #pragma unroll 8
    for (int j = 0; j < 128; ++j) acc += Ps[j] * Xb[(size_t)j * HD];
    part[((size_t)(b * 4 + q)) * HD + h] = acc;
}

// atxt[b*HD+h] = sum_q part[(b*4+q)*HD+h]
__global__ __launch_bounds__(256) void wsum_reduce(const float* __restrict__ part,
                                                   float* __restrict__ Y) {
    const int m = blockIdx.x * 256 + threadIdx.x;   // m = b*HD + h
    const int b = m / HD, h = m % HD;
    float s = 0.f;
    #pragma unroll
    for (int q = 0; q < 4; ++q) s += part[((size_t)(b * 4 + q)) * HD + h];
    Y[m] = s;
}

// ni/nt GEMV: grid (BD, HD/64, 2). Y = tanh(X[b,:] @ W + bias), k-split 4 ways.
__global__ __launch_bounds__(256) void ni_nt_kernel(
    const float* __restrict__ aimg, const float* __restrict__ atxt,
    const float* __restrict__ gi_w, const float* __restrict__ gi_b,
    const float* __restrict__ gt_w, const float* __restrict__ gt_b,
    float* __restrict__ ni, float* __restrict__ nt)
{
    const int b = blockIdx.x, n0 = blockIdx.y * 64, which = blockIdx.z;
    const float* X = which ? atxt : aimg;
    const float* W = which ? gt_w : gi_w;
    const float* bias = which ? gt_b : gi_b;
    float* Y = which ? nt : ni;

    __shared__ float Xs[HD];
    __shared__ float partial[4][64];
    const int t = threadIdx.x;
    for (int h = t; h < HD; h += 256) Xs[h] = X[b * HD + h];
    __syncthreads();
    const int n = n0 + (t & 63), kq = t >> 6;
    float acc = 0.f;
    const float* Wp = W + (size_t)(kq * 192) * HD + n;
    #pragma unroll 8
    for (int h = 0; h < 192; ++h) acc += Xs[kq * 192 + h] * Wp[(size_t)h * HD];
    partial[kq][t & 63] = acc;
    __syncthreads();
    if (t < 64) {
        const float s = partial[0][t] + partial[1][t] + partial[2][t] + partial[3][t];
        Y[b * HD + n0 + t] = tanhf(s + bias[n0 + t]);
    }
}

// per-batch: gate g, mm row, s_mm scalar
__global__ __launch_bounds__(256) void gate_mix(
    const float* __restrict__ ni, const float* __restrict__ nt,
    const float* __restrict__ gg_w, const float* __restrict__ gg_b,
    const float* __restrict__ v_m, const float* __restrict__ c_m,
    const float* __restrict__ fg_b,
    float* __restrict__ mm, float* __restrict__ s_mm)
{
    const int b = blockIdx.x, t = threadIdx.x;
    __shared__ float red[4];
    __shared__ float gsh;
    float acc = 0.f;
    for (int n = t; n < HD; n += 256)
        acc += ni[b * HD + n] * gg_w[n] + nt[b * HD + n] * gg_w[HD + n];
    for (int off = 32; off; off >>= 1) acc += __shfl_xor(acc, off);
    if ((t & 63) == 0) red[t >> 6] = acc;
    __syncthreads();
    if (t == 0) gsh = 1.f / (1.f + expf(-(red[0] + red[1] + red[2] + red[3] + gg_b[0])));
    __syncthreads();
    const float g = gsh;
    float a2 = 0.f;
    for (int n = t; n < HD; n += 256) {
        const float m = g * ni[b * HD + n] + (1.f - g) * nt[b * HD + n];
        mm[b * HD + n] = m;
        a2 += m * v_m[n];
    }
    for (int off = 32; off; off >>= 1) a2 += __shfl_xor(a2, off);
    __syncthreads();
    if ((t & 63) == 0) red[t >> 6] = a2;
    __syncthreads();
    if (t == 0) s_mm[b] = red[0] + red[1] + red[2] + red[3] + *c_m + fg_b[0];
}

// T = tanh(mm @ fr_w + fr_b): grid (BD, HD/64), same k-split structure
__global__ __launch_bounds__(256) void T_kernel(
    const float* __restrict__ mm, const float* __restrict__ fr_w,
    const float* __restrict__ fr_b, float* __restrict__ T)
{
    const int b = blockIdx.x, n0 = blockIdx.y * 64;
    __shared__ float Xs[HD];
    __shared__ float partial[4][64];
    const int t = threadIdx.x;
    for (int h = t; h < HD; h += 256) Xs[h] = mm[b * HD + h];
    __syncthreads();
    const int n = n0 + (t & 63), kq = t >> 6;
    float acc = 0.f;
    const float* Wp = fr_w + (size_t)(kq * 192) * HD + n;
    #pragma unroll 8
    for (int h = 0; h < 192; ++h) acc += Xs[kq * 192 + h] * Wp[(size_t)h * HD];
    partial[kq][t & 63] = acc;
    __syncthreads();
    if (t < 64) {
        const float s = partial[0][t] + partial[1][t] + partial[2][t] + partial[3][t];
        T[b * HD + n0 + t] = tanhf(s + fr_b[n0 + t]);
    }
}

// wave-per-row rank-1 collapses: v_f, v_m, c_m (coalesced row reads)
__global__ __launch_bounds__(256) void vf_vm_kernel(const float* __restrict__ ft_w,
                                                    const float* __restrict__ fm_w,
                                                    const float* __restrict__ fm_b,
                                                    const float* __restrict__ fg_w,
                                                    float* __restrict__ v_f,
                                                    float* __restrict__ v_m,
                                                    float* __restrict__ c_m) {
    const int idx = blockIdx.x * 4 + (threadIdx.x >> 6);
    const int lane = threadIdx.x & 63;
    const float* row; const float* vecp; float* outp;
    if (idx < HD)            { row = ft_w + (size_t)idx * HD;        vecp = fg_w;      outp = v_f + idx; }
    else if (idx < 2 * HD)   { row = fm_w + (size_t)(idx - HD) * HD; vecp = fg_w + HD; outp = v_m + (idx - HD); }
    else if (idx == 2 * HD)  { row = fm_b;                           vecp = fg_w + HD; outp = c_m; }
    else return;
    float acc = 0.f;
    #pragma unroll
    for (int i = 0; i < HD / 64; ++i) acc += row[lane + 64 * i] * vecp[lane + 64 * i];
    for (int off = 32; off; off >>= 1) acc += __shfl_xor(acc, off);
    if (lane == 0) *outp = acc;
}

// s_txt[row] = text[row,:] . v_f
__global__ __launch_bounds__(256) void stxt_kernel(const float* __restrict__ text,
                                                   const float* __restrict__ v_f,
                                                   float* __restrict__ s_txt) {
    const int row = blockIdx.x * 4 + (threadIdx.x >> 6);
    const int lane = threadIdx.x & 63;
    const float* tr = text + (size_t)row * HD;
    float acc = 0.f;
    #pragma unroll
    for (int i = 0; i < HD / 64; ++i)
        acc += tr[lane + 64 * i] * v_f[lane + 64 * i];
    for (int off = 32; off; off >>= 1) acc += __shfl_xor(acc, off);
    if (lane == 0) s_txt[row] = acc;
}

// out[b,s,h] = sigmoid(s_txt[b,s] + s_mm[b]) * T[b,h]  (reads ws only)
__global__ __launch_bounds__(256) void out_kernel(const float* __restrict__ s_txt,
                                                  const float* __restrict__ s_mm,
                                                  const float* __restrict__ T,
                                                  float* __restrict__ out) {
    const size_t idx = ((size_t)blockIdx.x * 256 + threadIdx.x) * 4;
    const int h = (int)(idx % HD);
    const int bs = (int)(idx / HD);
    const int b = bs >> 9;
    float f = s_txt[bs] + s_mm[b];
    f = 1.f / (1.f + expf(-f));
    const float* Tp = T + b * HD + h;
    f32x4 o;
    o[0] = f * Tp[0]; o[1] = f * Tp[1]; o[2] = f * Tp[2]; o[3] = f * Tp[3];
    *(f32x4*)(out + idx) = o;
}

// ---------------------------------------------------------------------------
extern "C" void kernel_launch(void* const* d_in, const int* in_sizes, int n_in,
                              void* d_out, int out_size, void* d_ws, size_t ws_size,
                              hipStream_t stream) {
    const float* text = (const float*)d_in[0];
    const float* img  = (const float*)d_in[1];
    const float* i1_w = (const float*)d_in[4];
    const float* a1_w = (const float*)d_in[5];
    const float* t2_w = (const float*)d_in[7];
    const float* a2_w = (const float*)d_in[10];
    const float* gt_w = (const float*)d_in[12];
    const float* gt_b = (const float*)d_in[13];
    const float* gi_w = (const float*)d_in[14];
    const float* gi_b = (const float*)d_in[15];
    const float* gg_w = (const float*)d_in[16];
    const float* gg_b = (const float*)d_in[17];
    const float* ft_w = (const float*)d_in[18];
    const float* fm_w = (const float*)d_in[19];
    const float* fm_b = (const float*)d_in[20];
    const float* fg_w = (const float*)d_in[21];
    const float* fg_b = (const float*)d_in[22];
    const float* fr_w = (const float*)d_in[23];
    const float* fr_b = (const float*)d_in[24];
    float* out = (float*)d_out;

    // ---- scratch inside d_out (12.58M floats; all uses precede out_kernel) ----
    float* sc_ = out;
    float* i_part  = sc_;                 // 1600*24 = 38400
    float* k_part  = sc_ + 38400;         // 16384*24 = 393216
    float* i_sc    = sc_ + 431616;        // 1600 (softmax in-place)
    float* k_sc    = sc_ + 433216;        // 16384 (softmax in-place)
    float* aimg    = sc_ + 449600;        // 24576
    float* atxt    = sc_ + 474176;        // 24576
    float* v_f     = sc_ + 498752;        // 768
    float* v_m     = sc_ + 499520;        // 768
    float* c_m     = sc_ + 500288;        // 1 (+pad)
    float* ws_part = sc_ + 500352;        // 32*4*768 = 98304
    float* ni      = sc_ + 598656;        // 24576
    float* nt      = sc_ + 623232;        // 24576
    float* mm      = sc_ + 647808;        // 24576  (total 672384 << 12.58M)

    // ---- ws holds only what out_kernel reads (164 KB) ----
    float* ws    = (float*)d_ws;
    float* s_txt = ws;                    // 16384
    float* s_mm  = ws + 16384;            // 32 (+pad)
    float* T     = ws + 16448;            // 24576

    // 1/2. score GEMMs + reductions
    gemm_tanh_dot<<<dim3((MI + 63) / 64, NB), dim3(256), 0, stream>>>(
        img, i1_w, a1_w + HD, i_part, MI, HD, HD);
    gemm_tanh_dot<<<dim3(MT / 64, NB), dim3(256), 0, stream>>>(
        text, t2_w, a2_w + HD, k_part, MT, HD, HD);
    reduce_nb<<<dim3(7), dim3(256), 0, stream>>>(i_part, i_sc, MI);
    reduce_nb<<<dim3(MT / 256), dim3(256), 0, stream>>>(k_part, k_sc, MT);
    // 3. rank-1 collapses (wave-per-row, coalesced)
    vf_vm_kernel<<<dim3((2 * HD + 1 + 3) / 4), dim3(256), 0, stream>>>(
        ft_w, fm_w, fm_b, fg_w, v_f, v_m, c_m);
    // 4/5. softmaxes in-place (query-side terms cancel along softmax axis)
    softmax_p1<<<dim3(BD), dim3(64), 0, stream>>>(i_sc, i_sc);
    softmax_p2<<<dim3(BD), dim3(256), 0, stream>>>(k_sc, k_sc);
    // 6/7. attended rows (s-independent -> one row per batch)
    wsum_rows<<<dim3(BD, HD / 256), dim3(256), 0, stream>>>(i_sc, img, aimg, RD);
    wsum_part<<<dim3(BD, HD / 256, 4), dim3(256), 0, stream>>>(k_sc, text, ws_part);
    wsum_reduce<<<dim3(BD * HD / 256), dim3(256), 0, stream>>>(ws_part, atxt);
    // 8. GMF: ni/nt (768 blocks), gate+mix+s_mm (32), T (384)
    ni_nt_kernel<<<dim3(BD, HD / 64, 2), dim3(256), 0, stream>>>(
        aimg, atxt, gi_w, gi_b, gt_w, gt_b, ni, nt);
    gate_mix<<<dim3(BD), dim3(256), 0, stream>>>(
        ni, nt, gg_w, gg_b, v_m, c_m, fg_b, mm, s_mm);
    T_kernel<<<dim3(BD, HD / 64), dim3(256), 0, stream>>>(mm, fr_w, fr_b, T);
    // 9. per-(b,s) text gate term
    stxt_kernel<<<dim3(MT / 4), dim3(256), 0, stream>>>(text, v_f, s_txt);
    // 10. output (reads ws only; overwrites all of d_out)
    out_kernel<<<dim3((MT * HD / 4) / 256), dim3(256), 0, stream>>>(s_txt, s_mm, T, out);
}

// Round 7
// 293.753 us; speedup vs baseline: 2.1310x; 1.1889x over previous
//
#include <hip/hip_runtime.h>
#include <hip/hip_bf16.h>
#include <math.h>

// Problem dims
constexpr int BD = 32;
constexpr int SD = 512;
constexpr int RD = 49;
constexpr int HD = 768;
constexpr int NB = HD / 64;    // 12 n-blocks in the score GEMMs
constexpr int NP = NB * 2;     // 24 partial slots per row
constexpr int MT = BD * SD;    // 16384
constexpr int MI = BD * RD;    // 1568 (gemm pads to 1600 rows)

typedef __bf16 bf16;
typedef __bf16 bf16x4 __attribute__((ext_vector_type(4)));
typedef __bf16 bf16x8 __attribute__((ext_vector_type(8)));
typedef float f32x4 __attribute__((ext_vector_type(4)));

// ---------------------------------------------------------------------------
// prep_text: text fp32 -> text_bf (bf16) AND s_txt[row] = text[row,:].v_f
// one wave per row; text fp32 is read exactly once in the whole pipeline.
// ---------------------------------------------------------------------------
__global__ __launch_bounds__(256) void prep_text(
    const float* __restrict__ text, const float* __restrict__ v_f,
    bf16* __restrict__ text_bf, float* __restrict__ s_txt)
{
    const int row = blockIdx.x * 4 + (threadIdx.x >> 6);
    const int lane = threadIdx.x & 63;
    const float* tr = text + (size_t)row * HD;
    bf16* tb = text_bf + (size_t)row * HD;
    float acc = 0.f;
    #pragma unroll
    for (int c = 0; c < 3; ++c) {
        const int o = c * 256 + lane * 4;
        const f32x4 x = *(const f32x4*)(tr + o);
        const f32x4 v = *(const f32x4*)(v_f + o);
        bf16x4 b; b[0] = (bf16)x[0]; b[1] = (bf16)x[1]; b[2] = (bf16)x[2]; b[3] = (bf16)x[3];
        *(bf16x4*)(tb + o) = b;
        acc += x[0] * v[0] + x[1] * v[1] + x[2] * v[2] + x[3] * v[3];
    }
    for (int off = 32; off; off >>= 1) acc += __shfl_xor(acc, off);
    if (lane == 0) s_txt[row] = acc;
}

// img fp32 -> bf16 (8 elems/thread)
__global__ __launch_bounds__(256) void conv_img(const float* __restrict__ src,
                                                bf16* __restrict__ dst, int n8) {
    const int i = blockIdx.x * 256 + threadIdx.x;
    if (i >= n8) return;
    const size_t o = (size_t)i * 8;
    const f32x4 x0 = *(const f32x4*)(src + o);
    const f32x4 x1 = *(const f32x4*)(src + o + 4);
    bf16x8 b;
    b[0]=(bf16)x0[0]; b[1]=(bf16)x0[1]; b[2]=(bf16)x0[2]; b[3]=(bf16)x0[3];
    b[4]=(bf16)x1[0]; b[5]=(bf16)x1[1]; b[6]=(bf16)x1[2]; b[7]=(bf16)x1[3];
    *(bf16x8*)(dst + o) = b;
}

// W (K x N fp32, row-major) -> Wt (N x K bf16, row-major). 64x64 LDS tiles.
// grid (12, 12, 2): z selects {t2_w->wt_t, i1_w->wt_i}
__global__ __launch_bounds__(256) void transpose_w(
    const float* __restrict__ w0, const float* __restrict__ w1,
    bf16* __restrict__ o0, bf16* __restrict__ o1)
{
    __shared__ float tile[64][65];
    const float* W = blockIdx.z ? w1 : w0;
    bf16* Wt = blockIdx.z ? o1 : o0;
    const int k0 = blockIdx.x * 64, n0 = blockIdx.y * 64;
    const int t = threadIdx.x;
    const int rb = t >> 6, c = t & 63;
    #pragma unroll
    for (int i = 0; i < 16; ++i) {
        const int r = rb + i * 4;
        tile[r][c] = W[(size_t)(k0 + r) * HD + n0 + c];
    }
    __syncthreads();
    #pragma unroll
    for (int i = 0; i < 16; ++i) {
        const int r = rb + i * 4;
        Wt[(size_t)(n0 + r) * HD + k0 + c] = (bf16)tile[c][r];
    }
}

// ---------------------------------------------------------------------------
// Score GEMM (bf16 in): part[m][by*2+half] = sum_{32-col half} tanh((A@W)[m,n])*vec[n]
// A: M x K bf16 row-major; Wt: N x K bf16 row-major (pre-transposed).
// Both tiles staged with identical conflict-free row loads + ds_write_b128.
// ---------------------------------------------------------------------------
__global__ __launch_bounds__(256) void gemm_bt(
    const bf16* __restrict__ A, const bf16* __restrict__ Wt,
    const float* __restrict__ vec, float* __restrict__ part, int M)
{
    __shared__ __align__(16) bf16 As[64][40];   // 80B rows (16B-aligned, 2-way max)
    __shared__ __align__(16) bf16 Bs[64][40];

    const int t = threadIdx.x;
    const int m0 = blockIdx.x * 64;
    const int n0 = blockIdx.y * 64;
    const int w = t >> 6, lane = t & 63;
    const int quad = lane >> 4, l16 = lane & 15;
    const int wm = (w >> 1) * 32, wn = (w & 1) * 32;

    const int r = t >> 2, c8 = (t & 3) * 8;     // 64 rows x 32 k per tile
    const int gm = m0 + r;
    const bf16* Ap = A + (size_t)gm * HD + c8;
    const bf16* Bp = Wt + (size_t)(n0 + r) * HD + c8;

    f32x4 acc[2][2] = {};

    for (int kk = 0; kk < HD; kk += 32) {
        bf16x8 av = {};
        if (gm < M) av = *(const bf16x8*)(Ap + kk);
        const bf16x8 bv = *(const bf16x8*)(Bp + kk);

        __syncthreads();
        *(bf16x8*)(&As[r][c8]) = av;
        *(bf16x8*)(&Bs[r][c8]) = bv;
        __syncthreads();

        const bf16x8 a0 = *(const bf16x8*)(&As[wm + l16][quad * 8]);
        const bf16x8 a1 = *(const bf16x8*)(&As[wm + 16 + l16][quad * 8]);
        const bf16x8 b0 = *(const bf16x8*)(&Bs[wn + l16][quad * 8]);
        const bf16x8 b1 = *(const bf16x8*)(&Bs[wn + 16 + l16][quad * 8]);
        acc[0][0] = __builtin_amdgcn_mfma_f32_16x16x32_bf16(a0, b0, acc[0][0], 0, 0, 0);
        acc[0][1] = __builtin_amdgcn_mfma_f32_16x16x32_bf16(a0, b1, acc[0][1], 0, 0, 0);
        acc[1][0] = __builtin_amdgcn_mfma_f32_16x16x32_bf16(a1, b0, acc[1][0], 0, 0, 0);
        acc[1][1] = __builtin_amdgcn_mfma_f32_16x16x32_bf16(a1, b1, acc[1][1], 0, 0, 0);
    }

    // epilogue: C/D layout col=lane&15, row=quad*4+reg
    #pragma unroll
    for (int ti = 0; ti < 2; ++ti)
      #pragma unroll
      for (int reg = 0; reg < 4; ++reg) {
          float p = 0.f;
          #pragma unroll
          for (int tj = 0; tj < 2; ++tj) {
              const int gn = n0 + wn + tj * 16 + l16;
              p += tanhf(acc[ti][tj][reg]) * vec[gn];
          }
          p += __shfl_xor(p, 1);
          p += __shfl_xor(p, 2);
          p += __shfl_xor(p, 4);
          p += __shfl_xor(p, 8);
          const int gm2 = m0 + wm + ti * 16 + quad * 4 + reg;
          if (l16 == 0) part[(size_t)gm2 * NP + blockIdx.y * 2 + (w & 1)] = p;
      }
}

// score[m] = sum_j part[m*NP+j]
__global__ __launch_bounds__(256) void reduce_nb(const float* __restrict__ part,
                                                 float* __restrict__ score, int M) {
    const int m = blockIdx.x * 256 + threadIdx.x;
    if (m < M) {
        float s = 0.f;
        #pragma unroll
        for (int j = 0; j < NP; ++j) s += part[(size_t)m * NP + j];
        score[m] = s;
    }
}

// softmax over R=49 per batch; safe in-place
__global__ __launch_bounds__(64) void softmax_p1(const float* sc, float* p1) {
    const int b = blockIdx.x, l = threadIdx.x;
    float x = (l < RD) ? sc[b * RD + l] : -1e30f;
    float m = x;
    for (int off = 32; off; off >>= 1) m = fmaxf(m, __shfl_xor(m, off));
    float e = (l < RD) ? expf(x - m) : 0.f;
    float s = e;
    for (int off = 32; off; off >>= 1) s += __shfl_xor(s, off);
    if (l < RD) p1[b * RD + l] = e / s;
}

// softmax over S=512 per batch; safe in-place
__global__ __launch_bounds__(256) void softmax_p2(const float* sc, float* p2) {
    const int b = blockIdx.x, t = threadIdx.x;
    __shared__ float red[4];
    const float x0 = sc[b * SD + t], x1 = sc[b * SD + 256 + t];
    float m = fmaxf(x0, x1);
    for (int off = 32; off; off >>= 1) m = fmaxf(m, __shfl_xor(m, off));
    if ((t & 63) == 0) red[t >> 6] = m;
    __syncthreads();
    m = fmaxf(fmaxf(red[0], red[1]), fmaxf(red[2], red[3]));
    const float e0 = expf(x0 - m), e1 = expf(x1 - m);
    float s = e0 + e1;
    for (int off = 32; off; off >>= 1) s += __shfl_xor(s, off);
    __syncthreads();
    if ((t & 63) == 0) red[t >> 6] = s;
    __syncthreads();
    s = red[0] + red[1] + red[2] + red[3];
    p2[b * SD + t] = e0 / s;
    p2[b * SD + 256 + t] = e1 / s;
}

// aimg[b,h] = sum_j P[b,j] * img[b,j,h]  (J=49, fp32 img)
__global__ __launch_bounds__(256) void wsum_rows(const float* __restrict__ P,
                                                 const float* __restrict__ X,
                                                 float* __restrict__ Y, int J) {
    const int b = blockIdx.x;
    const int h = blockIdx.y * 256 + threadIdx.x;
    __shared__ float Ps[SD];
    for (int j = threadIdx.x; j < J; j += 256) Ps[j] = P[b * J + j];
    __syncthreads();
    float acc = 0.f;
    const float* Xb = X + (size_t)b * J * HD + h;
    for (int j = 0; j < J; ++j) acc += Ps[j] * Xb[(size_t)j * HD];
    Y[b * HD + h] = acc;
}

// text wsum (bf16 text), j-split 4-way
__global__ __launch_bounds__(256) void wsum_part(const float* __restrict__ P,
                                                 const bf16* __restrict__ X,
                                                 float* __restrict__ part) {
    const int b = blockIdx.x;
    const int h = blockIdx.y * 256 + threadIdx.x;
    const int q = blockIdx.z;
    __shared__ float Ps[128];
    if (threadIdx.x < 128) Ps[threadIdx.x] = P[b * SD + q * 128 + threadIdx.x];
    __syncthreads();
    float acc = 0.f;
    const bf16* Xb = X + (size_t)b * SD * HD + (size_t)(q * 128) * HD + h;
    #pragma unroll 8
    for (int j = 0; j < 128; ++j) acc += Ps[j] * (float)Xb[(size_t)j * HD];
    part[((size_t)(b * 4 + q)) * HD + h] = acc;
}

__global__ __launch_bounds__(256) void wsum_reduce(const float* __restrict__ part,
                                                   float* __restrict__ Y) {
    const int m = blockIdx.x * 256 + threadIdx.x;
    const int b = m / HD, h = m % HD;
    float s = 0.f;
    #pragma unroll
    for (int q = 0; q < 4; ++q) s += part[((size_t)(b * 4 + q)) * HD + h];
    Y[m] = s;
}

// ni/nt GEMV: grid (BD, HD/64, 2)
__global__ __launch_bounds__(256) void ni_nt_kernel(
    const float* __restrict__ aimg, const float* __restrict__ atxt,
    const float* __restrict__ gi_w, const float* __restrict__ gi_b,
    const float* __restrict__ gt_w, const float* __restrict__ gt_b,
    float* __restrict__ ni, float* __restrict__ nt)
{
    const int b = blockIdx.x, n0 = blockIdx.y * 64, which = blockIdx.z;
    const float* X = which ? atxt : aimg;
    const float* W = which ? gt_w : gi_w;
    const float* bias = which ? gt_b : gi_b;
    float* Y = which ? nt : ni;

    __shared__ float Xs[HD];
    __shared__ float partial[4][64];
    const int t = threadIdx.x;
    for (int h = t; h < HD; h += 256) Xs[h] = X[b * HD + h];
    __syncthreads();
    const int n = n0 + (t & 63), kq = t >> 6;
    float acc = 0.f;
    const float* Wp = W + (size_t)(kq * 192) * HD + n;
    #pragma unroll 8
    for (int h = 0; h < 192; ++h) acc += Xs[kq * 192 + h] * Wp[(size_t)h * HD];
    partial[kq][t & 63] = acc;
    __syncthreads();
    if (t < 64) {
        const float s = partial[0][t] + partial[1][t] + partial[2][t] + partial[3][t];
        Y[b * HD + n0 + t] = tanhf(s + bias[n0 + t]);
    }
}

// per-batch: gate g, mm row, s_mm scalar
__global__ __launch_bounds__(256) void gate_mix(
    const float* __restrict__ ni, const float* __restrict__ nt,
    const float* __restrict__ gg_w, const float* __restrict__ gg_b,
    const float* __restrict__ v_m, const float* __restrict__ c_m,
    const float* __restrict__ fg_b,
    float* __restrict__ mm, float* __restrict__ s_mm)
{
    const int b = blockIdx.x, t = threadIdx.x;
    __shared__ float red[4];
    __shared__ float gsh;
    float acc = 0.f;
    for (int n = t; n < HD; n += 256)
        acc += ni[b * HD + n] * gg_w[n] + nt[b * HD + n] * gg_w[HD + n];
    for (int off = 32; off; off >>= 1) acc += __shfl_xor(acc, off);
    if ((t & 63) == 0) red[t >> 6] = acc;
    __syncthreads();
    if (t == 0) gsh = 1.f / (1.f + expf(-(red[0] + red[1] + red[2] + red[3] + gg_b[0])));
    __syncthreads();
    const float g = gsh;
    float a2 = 0.f;
    for (int n = t; n < HD; n += 256) {
        const float m = g * ni[b * HD + n] + (1.f - g) * nt[b * HD + n];
        mm[b * HD + n] = m;
        a2 += m * v_m[n];
    }
    for (int off = 32; off; off >>= 1) a2 += __shfl_xor(a2, off);
    __syncthreads();
    if ((t & 63) == 0) red[t >> 6] = a2;
    __syncthreads();
    if (t == 0) s_mm[b] = red[0] + red[1] + red[2] + red[3] + *c_m + fg_b[0];
}

// T = tanh(mm @ fr_w + fr_b): grid (BD, HD/64)
__global__ __launch_bounds__(256) void T_kernel(
    const float* __restrict__ mm, const float* __restrict__ fr_w,
    const float* __restrict__ fr_b, float* __restrict__ T)
{
    const int b = blockIdx.x, n0 = blockIdx.y * 64;
    __shared__ float Xs[HD];
    __shared__ float partial[4][64];
    const int t = threadIdx.x;
    for (int h = t; h < HD; h += 256) Xs[h] = mm[b * HD + h];
    __syncthreads();
    const int n = n0 + (t & 63), kq = t >> 6;
    float acc = 0.f;
    const float* Wp = fr_w + (size_t)(kq * 192) * HD + n;
    #pragma unroll 8
    for (int h = 0; h < 192; ++h) acc += Xs[kq * 192 + h] * Wp[(size_t)h * HD];
    partial[kq][t & 63] = acc;
    __syncthreads();
    if (t < 64) {
        const float s = partial[0][t] + partial[1][t] + partial[2][t] + partial[3][t];
        T[b * HD + n0 + t] = tanhf(s + fr_b[n0 + t]);
    }
}

// wave-per-row rank-1 collapses: v_f, v_m, c_m
__global__ __launch_bounds__(256) void vf_vm_kernel(const float* __restrict__ ft_w,
                                                    const float* __restrict__ fm_w,
                                                    const float* __restrict__ fm_b,
                                                    const float* __restrict__ fg_w,
                                                    float* __restrict__ v_f,
                                                    float* __restrict__ v_m,
                                                    float* __restrict__ c_m) {
    const int idx = blockIdx.x * 4 + (threadIdx.x >> 6);
    const int lane = threadIdx.x & 63;
    const float* row; const float* vecp; float* outp;
    if (idx < HD)            { row = ft_w + (size_t)idx * HD;        vecp = fg_w;      outp = v_f + idx; }
    else if (idx < 2 * HD)   { row = fm_w + (size_t)(idx - HD) * HD; vecp = fg_w + HD; outp = v_m + (idx - HD); }
    else if (idx == 2 * HD)  { row = fm_b;                           vecp = fg_w + HD; outp = c_m; }
    else return;
    float acc = 0.f;
    #pragma unroll
    for (int i = 0; i < HD / 64; ++i) acc += row[lane + 64 * i] * vecp[lane + 64 * i];
    for (int off = 32; off; off >>= 1) acc += __shfl_xor(acc, off);
    if (lane == 0) *outp = acc;
}

// out[b,s,h] = sigmoid(s_txt[b,s] + s_mm[b]) * T[b,h]  (reads ws only)
__global__ __launch_bounds__(256) void out_kernel(const float* __restrict__ s_txt,
                                                  const float* __restrict__ s_mm,
                                                  const float* __restrict__ T,
                                                  float* __restrict__ out) {
    const size_t idx = ((size_t)blockIdx.x * 256 + threadIdx.x) * 4;
    const int h = (int)(idx % HD);
    const int bs = (int)(idx / HD);
    const int b = bs >> 9;
    float f = s_txt[bs] + s_mm[b];
    f = 1.f / (1.f + expf(-f));
    const float* Tp = T + b * HD + h;
    f32x4 o;
    o[0] = f * Tp[0]; o[1] = f * Tp[1]; o[2] = f * Tp[2]; o[3] = f * Tp[3];
    *(f32x4*)(out + idx) = o;
}

// ---------------------------------------------------------------------------
extern "C" void kernel_launch(void* const* d_in, const int* in_sizes, int n_in,
                              void* d_out, int out_size, void* d_ws, size_t ws_size,
                              hipStream_t stream) {
    const float* text = (const float*)d_in[0];
    const float* img  = (const float*)d_in[1];
    const float* i1_w = (const float*)d_in[4];
    const float* a1_w = (const float*)d_in[5];
    const float* t2_w = (const float*)d_in[7];
    const float* a2_w = (const float*)d_in[10];
    const float* gt_w = (const float*)d_in[12];
    const float* gt_b = (const float*)d_in[13];
    const float* gi_w = (const float*)d_in[14];
    const float* gi_b = (const float*)d_in[15];
    const float* gg_w = (const float*)d_in[16];
    const float* gg_b = (const float*)d_in[17];
    const float* ft_w = (const float*)d_in[18];
    const float* fm_w = (const float*)d_in[19];
    const float* fm_b = (const float*)d_in[20];
    const float* fg_w = (const float*)d_in[21];
    const float* fg_b = (const float*)d_in[22];
    const float* fr_w = (const float*)d_in[23];
    const float* fr_b = (const float*)d_in[24];
    float* out = (float*)d_out;

    // ---- scratch inside d_out (12.58M floats; all uses precede out_kernel) ----
    float* sc_ = out;
    float* i_part  = sc_;                 // 38400
    float* k_part  = sc_ + 38400;         // 393216
    float* i_sc    = sc_ + 431616;        // 1600
    float* k_sc    = sc_ + 433216;        // 16384
    float* aimg    = sc_ + 449600;        // 24576
    float* atxt    = sc_ + 474176;        // 24576
    float* v_f     = sc_ + 498752;        // 768
    float* v_m     = sc_ + 499520;        // 768
    float* c_m     = sc_ + 500288;        // 1 (+pad)
    float* ws_part = sc_ + 500352;        // 98304
    float* ni      = sc_ + 598656;        // 24576
    float* nt      = sc_ + 623232;        // 24576
    float* mm      = sc_ + 647808;        // 24576
    bf16* text_bf  = (bf16*)(sc_ + 672384);    // 12.58M bf16 = 6291456 floats
    bf16* img_bf   = (bf16*)(sc_ + 6963840);   // 1204224 bf16 = 602112 floats
    bf16* wt_t     = (bf16*)(sc_ + 7565952);   // 589824 bf16 = 294912 floats
    bf16* wt_i     = (bf16*)(sc_ + 7860864);   // 589824 bf16  (ends 8155776 < 12.58M)

    // ---- ws holds only what out_kernel reads ----
    float* ws    = (float*)d_ws;
    float* s_txt = ws;                    // 16384
    float* s_mm  = ws + 16384;            // 32 (+pad)
    float* T     = ws + 16448;            // 24576

    // 0. rank-1 collapses first (prep_text needs v_f)
    vf_vm_kernel<<<dim3((2 * HD + 1 + 3) / 4), dim3(256), 0, stream>>>(
        ft_w, fm_w, fm_b, fg_w, v_f, v_m, c_m);
    // 0b. bf16 conversions + weight transposes
    prep_text<<<dim3(MT / 4), dim3(256), 0, stream>>>(text, v_f, text_bf, s_txt);
    conv_img<<<dim3((BD * RD * HD / 8 + 255) / 256), dim3(256), 0, stream>>>(
        img, img_bf, BD * RD * HD / 8);
    transpose_w<<<dim3(12, 12, 2), dim3(256), 0, stream>>>(t2_w, i1_w, wt_t, wt_i);
    // 1/2. score GEMMs + reductions
    gemm_bt<<<dim3((MI + 63) / 64, NB), dim3(256), 0, stream>>>(
        img_bf, wt_i, a1_w + HD, i_part, MI);
    gemm_bt<<<dim3(MT / 64, NB), dim3(256), 0, stream>>>(
        text_bf, wt_t, a2_w + HD, k_part, MT);
    reduce_nb<<<dim3(7), dim3(256), 0, stream>>>(i_part, i_sc, MI);
    reduce_nb<<<dim3(MT / 256), dim3(256), 0, stream>>>(k_part, k_sc, MT);
    // 4/5. softmaxes in-place (query-side terms cancel along softmax axis)
    softmax_p1<<<dim3(BD), dim3(64), 0, stream>>>(i_sc, i_sc);
    softmax_p2<<<dim3(BD), dim3(256), 0, stream>>>(k_sc, k_sc);
    // 6/7. attended rows (s-independent -> one row per batch)
    wsum_rows<<<dim3(BD, HD / 256), dim3(256), 0, stream>>>(i_sc, img, aimg, RD);
    wsum_part<<<dim3(BD, HD / 256, 4), dim3(256), 0, stream>>>(k_sc, text_bf, ws_part);
    wsum_reduce<<<dim3(BD * HD / 256), dim3(256), 0, stream>>>(ws_part, atxt);
    // 8. GMF
    ni_nt_kernel<<<dim3(BD, HD / 64, 2), dim3(256), 0, stream>>>(
        aimg, atxt, gi_w, gi_b, gt_w, gt_b, ni, nt);
    gate_mix<<<dim3(BD), dim3(256), 0, stream>>>(
        ni, nt, gg_w, gg_b, v_m, c_m, fg_b, mm, s_mm);
    T_kernel<<<dim3(BD, HD / 64), dim3(256), 0, stream>>>(mm, fr_w, fr_b, T);
    // 9. output (reads ws only; overwrites all of d_out)
    out_kernel<<<dim3((MT * HD / 4) / 256), dim3(256), 0, stream>>>(s_txt, s_mm, T, out);
}